// Round 1
// baseline (88.669 us; speedup 1.0000x reference)
//
#include <hip/hip_runtime.h>

#define NG      1024
#define W_IMG   192
#define H_IMG   192
#define HW      (W_IMG * H_IMG)
#define TILES_X 24
#define TILES_Y 24
#define NTILES  (TILES_X * TILES_Y)   // 576
#define TPB     256                   // 4 waves per block
#define TPBK    4                     // tiles per block (one per wave)
#define NBLK    (NTILES / TPBK)       // 144 blocks

// ---------------------------------------------------------------------------
// Single fused kernel.
//  - Each block redundantly preprocesses ALL 1024 gaussians into LDS (SoA).
//    (1024/256 = 4 gaussians per thread, ~1.2us, parallel across 144 CUs --
//     cheaper than a separate 4-CU kernel + launch serialization.)
//  - Block 0 additionally writes the per-gaussian outputs (radii/vis/means2D).
//  - Each wave then culls+sorts+composites ONE 8x8 tile:
//      * ballot compaction with in-register running count (no atomics)
//      * (depth,idx) packed into u64 key -> rank sort == stable argsort
//      * serial front-to-back composite, 64 lanes = 64 pixels
// ---------------------------------------------------------------------------
__global__ __launch_bounds__(TPB, 1) void render_fused(
    const float* __restrict__ means3D, const float* __restrict__ scales,
    const float* __restrict__ rotations, const float* __restrict__ opacities,
    const float* __restrict__ shs, const float* __restrict__ viewm,
    const float* __restrict__ projm, const float* __restrict__ campos,
    const float* __restrict__ bg, float* __restrict__ outp)
{
    __shared__ float4 sg0[NG];                     // gx, gy, radii, opa      16 KB
    __shared__ float4 sg1[NG];                     // conA, conB, conC, depth 16 KB
    __shared__ float4 sg2[NG];                     // r, g, b, 0              16 KB
    __shared__ unsigned long long skey[TPBK][NG];  // (depth_bits<<32)|idx    32 KB
    __shared__ unsigned short     ssrt[TPBK][NG];  // depth-ordered idx        8 KB

    const int t = threadIdx.x;

    // ---- uniform camera data (scalar loads) ----
    const float V0 = viewm[0],  V1 = viewm[1],  V2  = viewm[2],  V3  = viewm[3];
    const float V4 = viewm[4],  V5 = viewm[5],  V6  = viewm[6],  V7  = viewm[7];
    const float V8 = viewm[8],  V9 = viewm[9],  V10 = viewm[10], V11 = viewm[11];
    const float P0 = projm[0],  P1 = projm[1],  P2  = projm[2],  P3  = projm[3];
    const float P4 = projm[4],  P5 = projm[5],  P6  = projm[6],  P7  = projm[7];
    const float P12 = projm[12], P13 = projm[13], P14 = projm[14], P15 = projm[15];
    const float CX = campos[0], CY = campos[1], CZ = campos[2];

    // ================= phase 1: preprocess (all blocks, redundant) =========
#pragma unroll
    for (int j = 0; j < NG / TPB; ++j) {
        const int i = t + j * TPB;

        const float mx = means3D[i * 3 + 0];
        const float my = means3D[i * 3 + 1];
        const float mz = means3D[i * 3 + 2];

        // ---- SH degree-3 color ----
        float dxc = mx - CX, dyc = my - CY, dzc = mz - CZ;
        float nrm = sqrtf(dxc * dxc + dyc * dyc + dzc * dzc);
        float x = dxc / nrm, y = dyc / nrm, z = dzc / nrm;
        float xx = x * x, yy = y * y, zz = z * z;
        float xy = x * y, yz = y * z, xz = x * z;

        float basis[16];
        basis[0]  = 0.28209479177387814f;
        basis[1]  = -0.4886025119029199f * y;
        basis[2]  =  0.4886025119029199f * z;
        basis[3]  = -0.4886025119029199f * x;
        basis[4]  =  1.0925484305920792f * xy;
        basis[5]  = -1.0925484305920792f * yz;
        basis[6]  =  0.31539156525252005f * (2.f * zz - xx - yy);
        basis[7]  = -1.0925484305920792f * xz;
        basis[8]  =  0.5462742152960396f * (xx - yy);
        basis[9]  = -0.5900435899266435f * y * (3.f * xx - yy);
        basis[10] =  2.890611442640554f  * xy * z;
        basis[11] = -0.4570457994644658f * y * (4.f * zz - xx - yy);
        basis[12] =  0.3731763325901154f * z * (2.f * zz - 3.f * xx - 3.f * yy);
        basis[13] = -0.4570457994644658f * x * (4.f * zz - xx - yy);
        basis[14] =  1.445305721320277f  * z * (xx - yy);
        basis[15] = -0.5900435899266435f * x * (xx - yy - 3.f * zz);

        // vectorized SH load: 48 floats = 12 float4 per gaussian
        float sh[48];
        const float4* shv = (const float4*)shs + i * 12;
#pragma unroll
        for (int w = 0; w < 12; ++w) {
            float4 q4 = shv[w];
            sh[4 * w + 0] = q4.x; sh[4 * w + 1] = q4.y;
            sh[4 * w + 2] = q4.z; sh[4 * w + 3] = q4.w;
        }
        float cr = 0.f, cg = 0.f, cb = 0.f;
#pragma unroll
        for (int k = 0; k < 16; ++k) {
            float b = basis[k];
            cr += b * sh[3 * k + 0];
            cg += b * sh[3 * k + 1];
            cb += b * sh[3 * k + 2];
        }
        cr = fmaxf(cr + 0.5f, 0.f);
        cg = fmaxf(cg + 0.5f, 0.f);
        cb = fmaxf(cb + 0.5f, 0.f);

        // ---- cov3d = (R*S)(R*S)^T ----
        const float4 q = ((const float4*)rotations)[i];
        float qr = q.x, qx = q.y, qy = q.z, qz = q.w;
        float sx = scales[i * 3 + 0], sy = scales[i * 3 + 1], sz = scales[i * 3 + 2];
        float R00 = 1.f - 2.f * (qy * qy + qz * qz), R01 = 2.f * (qx * qy - qr * qz), R02 = 2.f * (qx * qz + qr * qy);
        float R10 = 2.f * (qx * qy + qr * qz), R11 = 1.f - 2.f * (qx * qx + qz * qz), R12 = 2.f * (qy * qz - qr * qx);
        float R20 = 2.f * (qx * qz - qr * qy), R21 = 2.f * (qy * qz + qr * qx), R22 = 1.f - 2.f * (qx * qx + qy * qy);
        float M00 = R00 * sx, M01 = R01 * sy, M02 = R02 * sz;
        float M10 = R10 * sx, M11 = R11 * sy, M12 = R12 * sz;
        float M20 = R20 * sx, M21 = R21 * sy, M22 = R22 * sz;
        float S00 = M00 * M00 + M01 * M01 + M02 * M02;
        float S01 = M00 * M10 + M01 * M11 + M02 * M12;
        float S02 = M00 * M20 + M01 * M21 + M02 * M22;
        float S11 = M10 * M10 + M11 * M11 + M12 * M12;
        float S12 = M10 * M20 + M11 * M21 + M12 * M22;
        float S22 = M20 * M20 + M21 * M21 + M22 * M22;

        // ---- view / proj transform ----
        float pv0 = V0 * mx + V1 * my + V2  * mz + V3;
        float pv1 = V4 * mx + V5 * my + V6  * mz + V7;
        float pv2 = V8 * mx + V9 * my + V10 * mz + V11;
        float ph0 = P0  * mx + P1  * my + P2  * mz + P3;
        float ph1 = P4  * mx + P5  * my + P6  * mz + P7;
        float ph3 = P12 * mx + P13 * my + P14 * mz + P15;
        float pp0 = ph0 / (ph3 + 1e-7f);
        float pp1 = ph1 / (ph3 + 1e-7f);
        float gx = ((pp0 + 1.f) * (float)W_IMG - 1.f) * 0.5f;
        float gy = ((pp1 + 1.f) * (float)H_IMG - 1.f) * 0.5f;

        float depth = pv2;
        bool in_front = depth > 0.2f;
        float tz = in_front ? depth : 1.f;
        const float lim = 1.3f * 0.5f;
        float txv = fminf(fmaxf(pv0 / tz, -lim), lim) * tz;
        float tyv = fminf(fmaxf(pv1 / tz, -lim), lim) * tz;
        const float fx = (float)W_IMG / (2.f * 0.5f);
        const float fy = (float)H_IMG / (2.f * 0.5f);
        float J00 = fx / tz, J02 = -fx * txv / (tz * tz);
        float J11 = fy / tz, J12 = -fy * tyv / (tz * tz);

        float T00 = J00 * V0 + J02 * V8;
        float T01 = J00 * V1 + J02 * V9;
        float T02 = J00 * V2 + J02 * V10;
        float T10 = J11 * V4 + J12 * V8;
        float T11 = J11 * V5 + J12 * V9;
        float T12 = J11 * V6 + J12 * V10;

        float u0 = T00 * S00 + T01 * S01 + T02 * S02;
        float u1 = T00 * S01 + T01 * S11 + T02 * S12;
        float u2 = T00 * S02 + T01 * S12 + T02 * S22;
        float w0 = T10 * S00 + T11 * S01 + T12 * S02;
        float w1 = T10 * S01 + T11 * S11 + T12 * S12;
        float w2 = T10 * S02 + T11 * S12 + T12 * S22;
        float c00 = u0 * T00 + u1 * T01 + u2 * T02;
        float c01 = u0 * T10 + u1 * T11 + u2 * T12;
        float c11 = w0 * T10 + w1 * T11 + w2 * T12;

        float a = c00 + 0.3f;
        float b = c01;
        float c = c11 + 0.3f;
        float det = a * c - b * b;
        bool pos_det = det > 0.f;
        float inv_det = pos_det ? 1.f / det : 0.f;
        float conA = c * inv_det, conB = -b * inv_det, conC = a * inv_det;
        float mid = 0.5f * (a + c);
        float lam = mid + sqrtf(fmaxf(mid * mid - det, 0.1f));
        bool visible = in_front && pos_det;
        float radii = visible ? ceilf(3.f * sqrtf(lam)) : 0.f;

        float opa = opacities[i];

        sg0[i] = make_float4(gx, gy, radii, visible ? opa : 0.f);
        sg1[i] = make_float4(conA, conB, conC, depth);
        sg2[i] = make_float4(cr, cg, cb, 0.f);

        if (blockIdx.x == 0) {
            outp[3 * HW + i]              = radii;
            outp[3 * HW + NG + i]         = (radii > 0.f) ? 1.f : 0.f;
            outp[3 * HW + 2 * NG + 2 * i]     = gx;
            outp[3 * HW + 2 * NG + 2 * i + 1] = gy;
        }
    }
    __syncthreads();

    // ================= phase 2: per-wave tile rasterization ================
    const int wave = t >> 6;
    const int lane = t & 63;
    const int tile = blockIdx.x * TPBK + wave;
    const int tileX = tile % TILES_X;
    const int tileY = tile / TILES_X;
    const float tx0 = (float)(tileX * 8);
    const float ty0 = (float)(tileY * 8);

    // ---- cull + compact (running base in register, no atomics) ----
    int m = 0;
#pragma unroll 4
    for (int it = 0; it < NG / 64; ++it) {
        const int g = it * 64 + lane;
        float4 g0 = sg0[g];
        bool hit = (g0.w > 0.f) &&
                   (g0.x >= tx0 - g0.z) && (g0.x <= tx0 + 7.f + g0.z) &&
                   (g0.y >= ty0 - g0.z) && (g0.y <= ty0 + 7.f + g0.z);
        unsigned long long mask = __ballot(hit);
        if (hit) {
            int pos = m + __popcll(mask & ((1ULL << lane) - 1ULL));
            // key = (depth_bits << 32) | idx : u64 compare == (depth, idx) lexicographic
            skey[wave][pos] =
                ((unsigned long long)__float_as_uint(sg1[g].w) << 32) | (unsigned)g;
        }
        m += __popcll(mask);
    }
    __syncthreads();   // order ds_writes before ds_reads (uniform barrier)

    // ---- rank sort: stable argsort by (depth, idx) ----
    for (int s = lane; s < m; s += 64) {
        const unsigned long long ks = skey[wave][s];
        int rank = 0;
        for (int j2 = 0; j2 < m; ++j2)
            rank += (skey[wave][j2] < ks) ? 1 : 0;
        ssrt[wave][rank] = (unsigned short)(ks & 0xFFFFu);
    }
    __syncthreads();

    // ---- composite: 64 lanes = 64 pixels, serial front-to-back ----
    const int lx = lane & 7, ly = lane >> 3;
    const int pxi = tileX * 8 + lx;
    const int pyi = tileY * 8 + ly;
    const float px = (float)pxi, py = (float)pyi;

    float T = 1.f, accR = 0.f, accG = 0.f, accB = 0.f;
    for (int k = 0; k < m; ++k) {
        const int gi = ssrt[wave][k];        // wave-uniform -> broadcast
        float4 g0 = sg0[gi];
        float4 g1 = sg1[gi];
        float4 g2 = sg2[gi];
        float dx = g0.x - px, dy = g0.y - py;
        bool cover = (fabsf(dx) <= g0.z) && (fabsf(dy) <= g0.z);
        float power = -0.5f * (g1.x * dx * dx + g1.z * dy * dy) - g1.y * dx * dy;
        float alpha = fminf(0.99f, g0.w * __expf(fminf(power, 0.f)));
        bool keep = cover && (power <= 0.f) && (alpha >= (1.f / 255.f));
        alpha = keep ? alpha : 0.f;
        float w = alpha * T;
        accR += w * g2.x;
        accG += w * g2.y;
        accB += w * g2.z;
        T *= (1.f - alpha);
    }

    const int pix = pyi * W_IMG + pxi;
    outp[pix]          = accR + T * bg[0];
    outp[HW + pix]     = accG + T * bg[1];
    outp[2 * HW + pix] = accB + T * bg[2];
}

// ---------------------------------------------------------------------------
extern "C" void kernel_launch(void* const* d_in, const int* in_sizes, int n_in,
                              void* d_out, int out_size, void* d_ws, size_t ws_size,
                              hipStream_t stream)
{
    const float* means3D   = (const float*)d_in[0];
    const float* scales    = (const float*)d_in[1];
    const float* rotations = (const float*)d_in[2];
    const float* opacities = (const float*)d_in[3];
    const float* shs       = (const float*)d_in[4];
    const float* viewm     = (const float*)d_in[5];
    const float* projm     = (const float*)d_in[6];
    const float* campos    = (const float*)d_in[7];
    const float* bg        = (const float*)d_in[8];

    float* outp = (float*)d_out;

    render_fused<<<NBLK, TPB, 0, stream>>>(
        means3D, scales, rotations, opacities, shs, viewm, projm, campos,
        bg, outp);
}